// Round 4
// baseline (23357.573 us; speedup 1.0000x reference)
//
#include <hip/hip_runtime.h>
#include <stdint.h>

#define T_STEPS 256
#define BATCH   256
#define OBS     128
#define HID     256
#define HSZ     512
#define RPG     32          // batch rows per group
#define NSLICES 64
#define HCS     8           // h-cols per slice
#define GCOLS   32          // gate cols per slice (HCS*4)

typedef __attribute__((ext_vector_type(8))) short short8;
typedef __attribute__((ext_vector_type(4))) float f32x4;

__device__ __forceinline__ unsigned short f2bf(float x) {
    union { float f; uint32_t u; } v; v.f = x;
    uint32_t r = v.u + 0x7FFF + ((v.u >> 16) & 1);
    return (unsigned short)(r >> 16);
}
__device__ __forceinline__ float bf2f(unsigned short h) {
    union { uint32_t u; float f; } v; v.u = ((uint32_t)h) << 16; return v.f;
}
__device__ __forceinline__ float sigmoidf_(float x) { return 1.f / (1.f + __expf(-x)); }
__device__ __forceinline__ float tanhf_(float x)    { return 1.f - 2.f / (1.f + __expf(2.f * x)); }

// ---------------- Encoder: feats = gelu(x @ W_enc + b_enc), bf16 out ----------------
__global__ __launch_bounds__(256) void enc_kernel(
    const float* __restrict__ x, const float* __restrict__ W_enc,
    const float* __restrict__ b_enc, unsigned short* __restrict__ feats) {
    __shared__ unsigned short wlds[HID * OBS];   // [n=256][k=128] bf16 swizzled, 64KB
    int tid = threadIdx.x;
    for (int idx = tid; idx < OBS * HID; idx += 256) {
        int k = idx >> 8, n = idx & 255;
        int byte = ((n * OBS + k) * 2) ^ ((n & 7) << 4);
        *(unsigned short*)((char*)wlds + byte) = f2bf(W_enc[k * HID + n]);
    }
    __syncthreads();
    int wave = tid >> 6, lane = tid & 63;
    long m0 = (long)blockIdx.x * 64 + wave * 16;
    int arow = lane & 15, kq = lane >> 4;
    f32x4 acc[16];
    f32x4 z4 = {0.f, 0.f, 0.f, 0.f};
#pragma unroll
    for (int i = 0; i < 16; i++) acc[i] = z4;
#pragma unroll
    for (int kk = 0; kk < OBS; kk += 32) {
        const float* ap = x + (m0 + arow) * OBS + kk + kq * 8;
        float4 a0 = *(const float4*)ap;
        float4 a1 = *(const float4*)(ap + 4);
        short8 af;
        af[0] = (short)f2bf(a0.x); af[1] = (short)f2bf(a0.y);
        af[2] = (short)f2bf(a0.z); af[3] = (short)f2bf(a0.w);
        af[4] = (short)f2bf(a1.x); af[5] = (short)f2bf(a1.y);
        af[6] = (short)f2bf(a1.z); af[7] = (short)f2bf(a1.w);
#pragma unroll
        for (int nt = 0; nt < 16; nt++) {
            int n = nt * 16 + arow;
            int byte = ((n * OBS + kk + kq * 8) * 2) ^ ((n & 7) << 4);
            short8 bf = *(const short8*)((char*)wlds + byte);
            acc[nt] = __builtin_amdgcn_mfma_f32_16x16x32_bf16(af, bf, acc[nt], 0, 0, 0);
        }
    }
#pragma unroll
    for (int nt = 0; nt < 16; nt++) {
        int col = nt * 16 + (lane & 15);
        float bias = b_enc[col];
#pragma unroll
        for (int j = 0; j < 4; j++) {
            long row = m0 + kq * 4 + j;
            float z = acc[nt][j] + bias;
            float zc = 0.79788456f * (z + 0.044715f * z * z * z);
            float g = 0.5f * z * (1.f + tanhf_(zc));
            feats[row * HID + col] = f2bf(g);
        }
    }
}

// ---------------- Prep: pack heads weights (bf16) + fill sigma (f32) ----------------
__global__ __launch_bounds__(256) void prep_kernel(
    const float* __restrict__ W_mu, const float* __restrict__ W_v,
    const float* __restrict__ log_std, unsigned short* __restrict__ Wpk,
    float* __restrict__ sigma_out) {
    int tid = blockIdx.x * 256 + threadIdx.x;      // 64*256 = 16384 threads
    int n = tid >> 9, k = tid & 511;               // Wpk [32][512]
    float w = 0.f;
    if (n < 16) w = W_mu[k * 16 + n];
    else if (n == 16) w = W_v[k];
    Wpk[n * HSZ + k] = f2bf(w);
    long base = (long)tid * 64;                    // sigma: 16384*64 = 1048576 f32
#pragma unroll 4
    for (int i = 0; i < 64; i++) {
        int col = (int)((base + i) & 15);
        sigma_out[base + i] = __expf(log_std[col]);
    }
}

// ---------------- Fused heads for one timestep (one WG per group) ----------------
__device__ __forceinline__ void heads_step(
    int u, int rowg, int wave, int arow, int kq,
    const unsigned short* __restrict__ hbuf, const unsigned short* __restrict__ Wpk,
    const float* __restrict__ b_mu, const float* __restrict__ b_v,
    float* __restrict__ mu_out, float* __restrict__ val_out) {
    const unsigned short* hb = hbuf + (u & 3) * (2 * BATCH * HSZ);
    int rt = wave >> 1, c0 = (wave & 1) * 16;
    const unsigned short* ha = hb + (rowg + rt * 16 + arow) * HSZ + kq * 8;
    f32x4 acc = {0.f, 0.f, 0.f, 0.f};
#pragma unroll
    for (int kk = 0; kk < HSZ; kk += 32) {
        short8 bw = *(const short8*)(Wpk + (c0 + arow) * HSZ + kk + kq * 8);
        short8 ah = *(const short8*)(ha + kk);
        acc = __builtin_amdgcn_mfma_f32_16x16x32_bf16(ah, bw, acc, 0, 0, 0);
        short8 al = *(const short8*)(ha + BATCH * HSZ + kk);
        acc = __builtin_amdgcn_mfma_f32_16x16x32_bf16(al, bw, acc, 0, 0, 0);
    }
    int col = c0 + arow;
    long rbase = (long)u * BATCH + rowg + rt * 16 + kq * 4;
    if (col < 16) {
        float bm = b_mu[col];
#pragma unroll
        for (int j = 0; j < 4; j++) mu_out[(rbase + j) * 16 + col] = acc[j] + bm;
    } else if (col == 16) {
        float bv = b_v[0];
#pragma unroll
        for (int j = 0; j < 4; j++) val_out[rbase + j] = acc[j] + bv;
    }
}

// ---------------- Persistent LSTM scan (normal launch, counter barrier) ----------------
// 512 WGs = 8 batch-groups x 64 h-col slices; LDS 52KB -> 3 WG/CU capacity,
// __launch_bounds__(256,2) caps VGPR<=128 -> >=2 WG/CU; 512 <= 256*2 co-resident.
__global__ __launch_bounds__(256, 2) void scan_kernel(
    const float* __restrict__ Wi, const float* __restrict__ Wh,
    const float* __restrict__ b_lstm, const unsigned short* __restrict__ feats,
    const unsigned short* __restrict__ Wpk, const float* __restrict__ b_mu,
    const float* __restrict__ b_v, unsigned short* __restrict__ hbuf,
    unsigned int* __restrict__ cnt, float* __restrict__ mu_out,
    float* __restrict__ val_out) {
    __shared__ unsigned short whs[GCOLS * HSZ];   // [n=32][k=512] bf16 swizzled, 32KB
    __shared__ unsigned short wis[GCOLS * HID];   // [n=32][k=256] bf16 swizzled, 16KB
    __shared__ float zt[RPG][GCOLS];              // 4KB
    const int tid = threadIdx.x;
    const int g = blockIdx.x & 7;
    const int slice = blockIdx.x >> 3;
    const int rowg = g * RPG;

    // Stage Wh/Wi slices: LDS col n -> global gate col (n&3)*512 + slice*8 + (n>>2)
    for (int idx = tid; idx < GCOLS * HSZ; idx += 256) {
        int n = idx & 31, k = idx >> 5;
        int colg = (n & 3) * HSZ + slice * HCS + (n >> 2);
        int byte = ((n * HSZ + k) * 2) ^ ((n & 7) << 4);
        *(unsigned short*)((char*)whs + byte) = f2bf(Wh[k * 2048 + colg]);
    }
    for (int idx = tid; idx < GCOLS * HID; idx += 256) {
        int n = idx & 31, k = idx >> 5;
        int colg = (n & 3) * HSZ + slice * HCS + (n >> 2);
        int byte = ((n * HID + k) * 2) ^ ((n & 7) << 4);
        *(unsigned short*)((char*)wis + byte) = f2bf(Wi[k * 2048 + colg]);
    }
    const int grow = tid >> 3, ghc = tid & 7;     // gate-phase (row, h-col) ownership
    float bl[4];
#pragma unroll
    for (int q = 0; q < 4; q++) bl[q] = b_lstm[q * HSZ + slice * HCS + ghc];
    float c = 0.f;
    const int wave = tid >> 6, lane = tid & 63;
    const int wr = (wave >> 1) * 16, wc = (wave & 1) * 16;
    const int arow = lane & 15, kq = lane >> 4;
    __syncthreads();

    for (int t = 0; t < T_STEPS; ++t) {
        f32x4 acc = {0.f, 0.f, 0.f, 0.f};
        // x-gate contribution (independent of h): issue before waiting on peers
        const unsigned short* fr = feats + ((long)t * BATCH + rowg + wr + arow) * HID + kq * 8;
#pragma unroll
        for (int kk = 0; kk < HID; kk += 32) {
            short8 af = *(const short8*)(fr + kk);
            int n = wc + arow;
            int byte = ((n * HID + kk + kq * 8) * 2) ^ ((n & 7) << 4);
            short8 bf = *(const short8*)((char*)wis + byte);
            acc = __builtin_amdgcn_mfma_f32_16x16x32_bf16(af, bf, acc, 0, 0, 0);
        }
        if (t > 0) {
            if (tid == 0) {
                while (__hip_atomic_load(&cnt[g * T_STEPS + t - 1], __ATOMIC_RELAXED,
                                         __HIP_MEMORY_SCOPE_AGENT) < (unsigned)NSLICES)
                    __builtin_amdgcn_s_sleep(1);
            }
            __syncthreads();        // all threads wait on the spin result
            __threadfence();        // acquire: hbuf[t-1] now visible
            const unsigned short* hb = hbuf + ((t - 1) & 3) * (2 * BATCH * HSZ);
            const unsigned short* hrh = hb + (rowg + wr + arow) * HSZ + kq * 8;
#pragma unroll
            for (int kk = 0; kk < HSZ; kk += 32) {
                int n = wc + arow;
                int byte = ((n * HSZ + kk + kq * 8) * 2) ^ ((n & 7) << 4);
                short8 bf = *(const short8*)((char*)whs + byte);
                short8 ah = *(const short8*)(hrh + kk);
                acc = __builtin_amdgcn_mfma_f32_16x16x32_bf16(ah, bf, acc, 0, 0, 0);
                short8 al = *(const short8*)(hrh + BATCH * HSZ + kk);
                acc = __builtin_amdgcn_mfma_f32_16x16x32_bf16(al, bf, acc, 0, 0, 0);
            }
        }
        // z tile -> LDS (C/D layout: col=lane&15, row=(lane>>4)*4+j)
#pragma unroll
        for (int j = 0; j < 4; j++) zt[wr + kq * 4 + j][wc + arow] = acc[j];
        __syncthreads();
        // gate math: one (row, h-col) per thread; c stays in a register
        float zi = zt[grow][ghc * 4 + 0] + bl[0];
        float zf = zt[grow][ghc * 4 + 1] + bl[1];
        float zg = zt[grow][ghc * 4 + 2] + bl[2];
        float zo = zt[grow][ghc * 4 + 3] + bl[3];
        c = sigmoidf_(zf) * c + sigmoidf_(zi) * tanhf_(zg);
        float h = sigmoidf_(zo) * tanhf_(c);
        unsigned short hhi = f2bf(h);
        unsigned short hlo = f2bf(h - bf2f(hhi));   // split-precision residual
        unsigned short* ho = hbuf + (t & 3) * (2 * BATCH * HSZ)
                           + (rowg + grow) * HSZ + slice * HCS + ghc;
        ho[0] = hhi;
        ho[BATCH * HSZ] = hlo;
        __threadfence();            // release: h visible device-wide before signaling
        __syncthreads();
        if (tid == 0)
            __hip_atomic_fetch_add(&cnt[g * T_STEPS + t], 1u, __ATOMIC_ACQ_REL,
                                   __HIP_MEMORY_SCOPE_AGENT);
        // fused heads for t-1, rotating designated slice; 4-slot hbuf makes the
        // post-signal read race-free (slot t-1 overwritten only at t+3, which
        // requires this WG's signal of t+2 -> after heads(t-1) completes).
        if (t > 0 && slice == ((t - 1) & 63))
            heads_step(t - 1, rowg, wave, arow, kq, hbuf, Wpk, b_mu, b_v, mu_out, val_out);
    }
    // heads for the final timestep (needs all slices' h[255])
    if (slice == ((T_STEPS - 1) & 63)) {
        if (tid == 0) {
            while (__hip_atomic_load(&cnt[g * T_STEPS + T_STEPS - 1], __ATOMIC_RELAXED,
                                     __HIP_MEMORY_SCOPE_AGENT) < (unsigned)NSLICES)
                __builtin_amdgcn_s_sleep(1);
        }
        __syncthreads();
        __threadfence();
        heads_step(T_STEPS - 1, rowg, wave, arow, kq, hbuf, Wpk, b_mu, b_v, mu_out, val_out);
    }
}

extern "C" void kernel_launch(void* const* d_in, const int* in_sizes, int n_in,
                              void* d_out, int out_size, void* d_ws, size_t ws_size,
                              hipStream_t stream) {
    const float* x      = (const float*)d_in[0];
    const float* W_enc  = (const float*)d_in[1];
    const float* b_enc  = (const float*)d_in[2];
    const float* Wi     = (const float*)d_in[3];
    const float* Wh     = (const float*)d_in[4];
    const float* b_lstm = (const float*)d_in[5];
    const float* W_mu   = (const float*)d_in[6];
    const float* b_mu   = (const float*)d_in[7];
    const float* lstd   = (const float*)d_in[8];
    const float* W_v    = (const float*)d_in[9];
    const float* b_v    = (const float*)d_in[10];

    char* ws = (char*)d_ws;
    unsigned int*   cnt   = (unsigned int*)ws;                      // 8KB counters
    unsigned short* Wpk   = (unsigned short*)(ws + 32768);          // 32KB packed heads W
    unsigned short* hbuf  = (unsigned short*)(ws + 65536);          // 2MB: 4 slots x (hi,lo) x 256 x 512
    unsigned short* feats = (unsigned short*)(ws + 65536 + 2097152);// 33.5MB bf16
    // total ws use: ~35.7MB

    float* mu_out  = (float*)d_out;                 // (T*B,16) f32
    float* sig_out = mu_out + 1048576;              // (T*B,16) f32
    float* val_out = mu_out + 2097152;              // (T*B,)   f32

    hipMemsetAsync(cnt, 0, 8 * T_STEPS * sizeof(unsigned int), stream);
    enc_kernel<<<dim3(1024), dim3(256), 0, stream>>>(x, W_enc, b_enc, feats);
    prep_kernel<<<dim3(64), dim3(256), 0, stream>>>(W_mu, W_v, lstd, Wpk, sig_out);
    scan_kernel<<<dim3(512), dim3(256), 0, stream>>>(Wi, Wh, b_lstm, feats, Wpk,
                                                     b_mu, b_v, hbuf, cnt,
                                                     mu_out, val_out);
}

// Round 6
// 4909.852 us; speedup vs baseline: 4.7573x; 4.7573x over previous
//
#include <hip/hip_runtime.h>
#include <stdint.h>

#define T_STEPS 256
#define BATCH   256
#define OBS     128
#define HID     256
#define HSZ     512
#define RPG     32          // batch rows per group
#define NSLICES 64
#define HCS     8           // h-cols per slice
#define GCOLS   32          // gate cols per slice (HCS*4)
#define RING_SLOT_W 131072  // u32 words per ring slot: 2 planes x 256 x 256
#define LO_OFF_W    65536   // u32 offset of lo plane within slot

typedef __attribute__((ext_vector_type(8))) short short8;
typedef __attribute__((ext_vector_type(4))) float f32x4;

__device__ __forceinline__ unsigned short f2bf(float x) {
    union { float f; uint32_t u; } v; v.f = x;
    uint32_t r = v.u + 0x7FFF + ((v.u >> 16) & 1);
    return (unsigned short)(r >> 16);
}
__device__ __forceinline__ float bf2f(unsigned short h) {
    union { uint32_t u; float f; } v; v.u = ((uint32_t)h) << 16; return v.f;
}
__device__ __forceinline__ float sigmoidf_(float x) { return 1.f / (1.f + __expf(-x)); }
__device__ __forceinline__ float tanhf_(float x)    { return 1.f - 2.f / (1.f + __expf(2.f * x)); }

// ---------------- Encoder: feats = gelu(x @ W_enc + b_enc), bf16 out ----------------
__global__ __launch_bounds__(256) void enc_kernel(
    const float* __restrict__ x, const float* __restrict__ W_enc,
    const float* __restrict__ b_enc, unsigned short* __restrict__ feats) {
    __shared__ unsigned short wlds[HID * OBS];   // [n=256][k=128] bf16 swizzled, 64KB
    int tid = threadIdx.x;
    for (int idx = tid; idx < OBS * HID; idx += 256) {
        int k = idx >> 8, n = idx & 255;
        int byte = ((n * OBS + k) * 2) ^ ((n & 7) << 4);
        *(unsigned short*)((char*)wlds + byte) = f2bf(W_enc[k * HID + n]);
    }
    __syncthreads();
    int wave = tid >> 6, lane = tid & 63;
    long m0 = (long)blockIdx.x * 64 + wave * 16;
    int arow = lane & 15, kq = lane >> 4;
    f32x4 acc[16];
    f32x4 z4 = {0.f, 0.f, 0.f, 0.f};
#pragma unroll
    for (int i = 0; i < 16; i++) acc[i] = z4;
#pragma unroll
    for (int kk = 0; kk < OBS; kk += 32) {
        const float* ap = x + (m0 + arow) * OBS + kk + kq * 8;
        float4 a0 = *(const float4*)ap;
        float4 a1 = *(const float4*)(ap + 4);
        short8 af;
        af[0] = (short)f2bf(a0.x); af[1] = (short)f2bf(a0.y);
        af[2] = (short)f2bf(a0.z); af[3] = (short)f2bf(a0.w);
        af[4] = (short)f2bf(a1.x); af[5] = (short)f2bf(a1.y);
        af[6] = (short)f2bf(a1.z); af[7] = (short)f2bf(a1.w);
#pragma unroll
        for (int nt = 0; nt < 16; nt++) {
            int n = nt * 16 + arow;
            int byte = ((n * OBS + kk + kq * 8) * 2) ^ ((n & 7) << 4);
            short8 bf = *(const short8*)((char*)wlds + byte);
            acc[nt] = __builtin_amdgcn_mfma_f32_16x16x32_bf16(af, bf, acc[nt], 0, 0, 0);
        }
    }
#pragma unroll
    for (int nt = 0; nt < 16; nt++) {
        int col = nt * 16 + (lane & 15);
        float bias = b_enc[col];
#pragma unroll
        for (int j = 0; j < 4; j++) {
            long row = m0 + kq * 4 + j;
            float z = acc[nt][j] + bias;
            float zc = 0.79788456f * (z + 0.044715f * z * z * z);
            float g = 0.5f * z * (1.f + tanhf_(zc));
            feats[row * HID + col] = f2bf(g);
        }
    }
}

// Parallel 64-lane poll: lane i waits for flag[i] != 0 (call with tid < 64 only).
__device__ __forceinline__ void spin_flags(const uint32_t* fl, int lane) {
    const uint32_t* p = fl + lane;
    while (!__all(__hip_atomic_load(p, __ATOMIC_RELAXED, __HIP_MEMORY_SCOPE_AGENT) != 0u)) {}
}

// ---------------- Persistent LSTM scan (flag barrier, agent-coherent ring) ----------------
// 512 WGs = 8 batch-groups x 64 h-col slices; LDS 52KB + VGPR cap -> 2 WG/CU -> all resident.
__global__ __launch_bounds__(256, 2) void scan_kernel(
    const float* __restrict__ Wi, const float* __restrict__ Wh,
    const float* __restrict__ b_lstm, const unsigned short* __restrict__ feats,
    uint32_t* __restrict__ ring, uint32_t* __restrict__ flags,
    unsigned short* __restrict__ hs) {
    __shared__ unsigned short whs[GCOLS * HSZ];   // [n=32][k=512] bf16 swizzled, 32KB
    __shared__ unsigned short wis[GCOLS * HID];   // [n=32][k=256] bf16 swizzled, 16KB
    __shared__ float zt[RPG][GCOLS];              // 4KB
    const int tid = threadIdx.x;
    const int g = blockIdx.x & 7;
    const int slice = blockIdx.x >> 3;
    const int rowg = g * RPG;

    // Stage Wh/Wi slices: LDS col n -> global gate col (n&3)*512 + slice*8 + (n>>2)
    for (int idx = tid; idx < GCOLS * HSZ; idx += 256) {
        int n = idx & 31, k = idx >> 5;
        int colg = (n & 3) * HSZ + slice * HCS + (n >> 2);
        int byte = ((n * HSZ + k) * 2) ^ ((n & 7) << 4);
        *(unsigned short*)((char*)whs + byte) = f2bf(Wh[k * 2048 + colg]);
    }
    for (int idx = tid; idx < GCOLS * HID; idx += 256) {
        int n = idx & 31, k = idx >> 5;
        int colg = (n & 3) * HSZ + slice * HCS + (n >> 2);
        int byte = ((n * HID + k) * 2) ^ ((n & 7) << 4);
        *(unsigned short*)((char*)wis + byte) = f2bf(Wi[k * 2048 + colg]);
    }
    const int grow = tid >> 3, ghc = tid & 7;     // gate-phase (row, h-col) ownership
    float bl[4];
#pragma unroll
    for (int q = 0; q < 4; q++) bl[q] = b_lstm[q * HSZ + slice * HCS + ghc];
    float c = 0.f;
    const int wave = tid >> 6, lane = tid & 63;
    const int wr = (wave >> 1) * 16, wc = (wave & 1) * 16;
    const int arow = lane & 15, kq = lane >> 4;
    __syncthreads();

    for (int t = 0; t < T_STEPS; ++t) {
        f32x4 acc = {0.f, 0.f, 0.f, 0.f};
        // x-gate contribution (independent of h): issue before waiting on peers
        const unsigned short* fr = feats + ((long)t * BATCH + rowg + wr + arow) * HID + kq * 8;
#pragma unroll
        for (int kk = 0; kk < HID; kk += 32) {
            short8 af = *(const short8*)(fr + kk);
            int n = wc + arow;
            int byte = ((n * HID + kk + kq * 8) * 2) ^ ((n & 7) << 4);
            short8 bf = *(const short8*)((char*)wis + byte);
            acc = __builtin_amdgcn_mfma_f32_16x16x32_bf16(af, bf, acc, 0, 0, 0);
        }
        if (t > 0) {
            if (tid < 64) spin_flags(flags + ((long)g * T_STEPS + t - 1) * 64, lane);
            __syncthreads();
            // agent-coherent (cache-bypassing) loads of h hi/lo planes; issue all
            // 64 up front so only one L3 round-trip latency is exposed.
            const unsigned long long* bh =
                (const unsigned long long*)(ring + ((t - 1) & 3) * RING_SLOT_W
                                            + (rowg + wr + arow) * 256) + kq * 2;
            const unsigned long long* bl2 = bh + LO_OFF_W / 2;
            unsigned long long qh[32], ql[32];
#pragma unroll
            for (int i = 0; i < 16; i++) {
                qh[2*i]   = __hip_atomic_load(bh + i*8,     __ATOMIC_RELAXED, __HIP_MEMORY_SCOPE_AGENT);
                qh[2*i+1] = __hip_atomic_load(bh + i*8 + 1, __ATOMIC_RELAXED, __HIP_MEMORY_SCOPE_AGENT);
                ql[2*i]   = __hip_atomic_load(bl2 + i*8,     __ATOMIC_RELAXED, __HIP_MEMORY_SCOPE_AGENT);
                ql[2*i+1] = __hip_atomic_load(bl2 + i*8 + 1, __ATOMIC_RELAXED, __HIP_MEMORY_SCOPE_AGENT);
            }
#pragma unroll
            for (int i = 0; i < 16; i++) {
                int n = wc + arow;
                int byte = ((n * HSZ + i * 32 + kq * 8) * 2) ^ ((n & 7) << 4);
                short8 bf = *(const short8*)((char*)whs + byte);
                union { unsigned long long q[2]; short8 s; } uh, ul;
                uh.q[0] = qh[2*i]; uh.q[1] = qh[2*i+1];
                ul.q[0] = ql[2*i]; ul.q[1] = ql[2*i+1];
                acc = __builtin_amdgcn_mfma_f32_16x16x32_bf16(uh.s, bf, acc, 0, 0, 0);
                acc = __builtin_amdgcn_mfma_f32_16x16x32_bf16(ul.s, bf, acc, 0, 0, 0);
            }
        }
        // z tile -> LDS (C/D layout: col=lane&15, row=(lane>>4)*4+j)
#pragma unroll
        for (int j = 0; j < 4; j++) zt[wr + kq * 4 + j][wc + arow] = acc[j];
        __syncthreads();
        // gate math: one (row, h-col) per thread; c stays in a register
        float zi = zt[grow][ghc * 4 + 0] + bl[0];
        float zf = zt[grow][ghc * 4 + 1] + bl[1];
        float zg = zt[grow][ghc * 4 + 2] + bl[2];
        float zo = zt[grow][ghc * 4 + 3] + bl[3];
        c = sigmoidf_(zf) * c + sigmoidf_(zi) * tanhf_(zg);
        float h = sigmoidf_(zo) * tanhf_(c);
        unsigned short hhi = f2bf(h);
        unsigned short hlo = f2bf(h - bf2f(hhi));   // split-precision residual
        // pair with tid^1: even thread stores the hi-plane word, odd the lo-plane word
        uint32_t mine = (uint32_t)hhi | ((uint32_t)hlo << 16);
        uint32_t part = __shfl_xor(mine, 1);
        int pairw = slice * 4 + (ghc >> 1);
        uint32_t wv;
        uint32_t* wp;
        if ((ghc & 1) == 0) {
            wv = (mine & 0xffffu) | (part << 16);           // [hi_c | hi_c+1]
            wp = ring + (t & 3) * RING_SLOT_W + (rowg + grow) * 256 + pairw;
        } else {
            wv = (part >> 16) | (mine & 0xffff0000u);       // [lo_c | lo_c+1]
            wp = ring + (t & 3) * RING_SLOT_W + LO_OFF_W + (rowg + grow) * 256 + pairw;
        }
        __hip_atomic_store(wp, wv, __ATOMIC_RELAXED, __HIP_MEMORY_SCOPE_AGENT);
        hs[((long)t * BATCH + rowg + grow) * HSZ + slice * HCS + ghc] = hhi; // for heads
        __syncthreads();            // drains vmcnt(0) before s_barrier -> stores visible
        if (tid == 0)
            __hip_atomic_store(flags + ((long)g * T_STEPS + t) * 64 + slice, 1u,
                               __ATOMIC_RELAXED, __HIP_MEMORY_SCOPE_AGENT);
    }
}

// ---------------- Heads: mu/sigma/value from hs (separate dispatch) ----------------
__global__ __launch_bounds__(256) void heads_kernel(
    const unsigned short* __restrict__ hs, const float* __restrict__ W_mu,
    const float* __restrict__ b_mu, const float* __restrict__ log_std,
    const float* __restrict__ W_v, const float* __restrict__ b_v,
    float* __restrict__ mu_out, float* __restrict__ sig_out,
    float* __restrict__ val_out) {
    __shared__ unsigned short wlds[32 * HSZ];     // [n=32][k=512]: 0-15 mu, 16 v, rest 0
    int tid = threadIdx.x;
    for (int idx = tid; idx < 32 * HSZ; idx += 256) {
        int n = idx & 31, k = idx >> 5;
        float w = 0.f;
        if (n < 16) w = W_mu[k * 16 + n];
        else if (n == 16) w = W_v[k];
        int byte = ((n * HSZ + k) * 2) ^ ((n & 7) << 4);
        *(unsigned short*)((char*)wlds + byte) = f2bf(w);
    }
    __syncthreads();
    int wave = tid >> 6, lane = tid & 63;
    long m0 = (long)blockIdx.x * 64 + wave * 16;
    int arow = lane & 15, kq = lane >> 4;
    f32x4 acc0 = {0.f, 0.f, 0.f, 0.f}, acc1 = {0.f, 0.f, 0.f, 0.f};
    const unsigned short* hr = hs + (m0 + arow) * HSZ + kq * 8;
#pragma unroll
    for (int kk = 0; kk < HSZ; kk += 32) {
        short8 af = *(const short8*)(hr + kk);
        int n0 = arow;
        int b0 = ((n0 * HSZ + kk + kq * 8) * 2) ^ ((n0 & 7) << 4);
        short8 bf0 = *(const short8*)((char*)wlds + b0);
        acc0 = __builtin_amdgcn_mfma_f32_16x16x32_bf16(af, bf0, acc0, 0, 0, 0);
        int n1 = 16 + arow;
        int b1 = ((n1 * HSZ + kk + kq * 8) * 2) ^ ((n1 & 7) << 4);
        short8 bf1 = *(const short8*)((char*)wlds + b1);
        acc1 = __builtin_amdgcn_mfma_f32_16x16x32_bf16(af, bf1, acc1, 0, 0, 0);
    }
    int col = lane & 15;
    float bm = b_mu[col];
    float sg = __expf(log_std[col]);
#pragma unroll
    for (int j = 0; j < 4; j++) {
        long row = m0 + kq * 4 + j;
        mu_out[row * 16 + col]  = acc0[j] + bm;
        sig_out[row * 16 + col] = sg;
    }
    if (col == 0) {
        float bv = b_v[0];
#pragma unroll
        for (int j = 0; j < 4; j++) {
            long row = m0 + kq * 4 + j;
            val_out[row] = acc1[j] + bv;
        }
    }
}

extern "C" void kernel_launch(void* const* d_in, const int* in_sizes, int n_in,
                              void* d_out, int out_size, void* d_ws, size_t ws_size,
                              hipStream_t stream) {
    const float* x      = (const float*)d_in[0];
    const float* W_enc  = (const float*)d_in[1];
    const float* b_enc  = (const float*)d_in[2];
    const float* Wi     = (const float*)d_in[3];
    const float* Wh     = (const float*)d_in[4];
    const float* b_lstm = (const float*)d_in[5];
    const float* W_mu   = (const float*)d_in[6];
    const float* b_mu   = (const float*)d_in[7];
    const float* lstd   = (const float*)d_in[8];
    const float* W_v    = (const float*)d_in[9];
    const float* b_v    = (const float*)d_in[10];

    char* ws = (char*)d_ws;
    uint32_t*       flags = (uint32_t*)ws;                            // 512KB flags
    uint32_t*       ring  = (uint32_t*)(ws + (512 << 10));            // 2MB: 4 slots x (hi,lo) x 256x512 bf16
    unsigned short* feats = (unsigned short*)(ws + (2560 << 10));     // 33.6MB bf16
    unsigned short* hs    = (unsigned short*)(ws + (2560 << 10) + 33554432); // 67.1MB bf16
    // total ws use: ~103.2MB

    float* mu_out  = (float*)d_out;                 // (T*B,16) f32
    float* sig_out = mu_out + 1048576;              // (T*B,16) f32
    float* val_out = mu_out + 2097152;              // (T*B,)   f32

    hipMemsetAsync(flags, 0, 8 * T_STEPS * 64 * sizeof(uint32_t), stream);
    enc_kernel<<<dim3(1024), dim3(256), 0, stream>>>(x, W_enc, b_enc, feats);
    scan_kernel<<<dim3(512), dim3(256), 0, stream>>>(Wi, Wh, b_lstm, feats,
                                                     ring, flags, hs);
    heads_kernel<<<dim3(1024), dim3(256), 0, stream>>>(hs, W_mu, b_mu, lstd, W_v, b_v,
                                                       mu_out, sig_out, val_out);
}

// Round 7
// 1312.250 us; speedup vs baseline: 17.7996x; 3.7416x over previous
//
#include <hip/hip_runtime.h>
#include <stdint.h>

#define T_STEPS 256
#define BATCH   256
#define OBS     128
#define HID     256
#define HSZ     512
#define RPG     32          // batch rows per group
#define NSLICES 32          // h-col slices per group
#define HCS     16          // h-cols per slice
#define GCOLS   64          // gate cols per slice (HCS*4)
#define RING_SLOT_W 65536   // u32 words per ring slot: 256 rows x 256 col-pairs (hi only)

typedef __attribute__((ext_vector_type(8))) short short8;
typedef __attribute__((ext_vector_type(4))) float f32x4;
typedef __attribute__((ext_vector_type(4))) int   i32x4;

__device__ __forceinline__ unsigned short f2bf(float x) {
    union { float f; uint32_t u; } v; v.f = x;
    uint32_t r = v.u + 0x7FFF + ((v.u >> 16) & 1);
    return (unsigned short)(r >> 16);
}
__device__ __forceinline__ float sigmoidf_(float x) { return 1.f / (1.f + __expf(-x)); }
__device__ __forceinline__ float tanhf_(float x)    { return 1.f - 2.f / (1.f + __expf(2.f * x)); }

// 4 coherent (L1/L2-bypass -> L3) 16B loads; "=&v" early-clobber so results can
// never alias the address register while loads are in flight (Round-5 bug).
#define GLD4(d0, d1, d2, d3, p, O0, O1, O2, O3)                                 \
    asm volatile("global_load_dwordx4 %0, %4, off offset:" #O0 " sc0 sc1\n\t"   \
                 "global_load_dwordx4 %1, %4, off offset:" #O1 " sc0 sc1\n\t"   \
                 "global_load_dwordx4 %2, %4, off offset:" #O2 " sc0 sc1\n\t"   \
                 "global_load_dwordx4 %3, %4, off offset:" #O3 " sc0 sc1"       \
                 : "=&v"(d0), "=&v"(d1), "=&v"(d2), "=&v"(d3) : "v"(p))

// ---------------- Encoder: feats = gelu(x @ W_enc + b_enc), bf16 out ----------------
__global__ __launch_bounds__(256) void enc_kernel(
    const float* __restrict__ x, const float* __restrict__ W_enc,
    const float* __restrict__ b_enc, unsigned short* __restrict__ feats) {
    __shared__ unsigned short wlds[HID * OBS];   // [n=256][k=128] bf16 swizzled, 64KB
    int tid = threadIdx.x;
    for (int idx = tid; idx < OBS * HID; idx += 256) {
        int k = idx >> 8, n = idx & 255;
        int byte = ((n * OBS + k) * 2) ^ ((n & 7) << 4);
        *(unsigned short*)((char*)wlds + byte) = f2bf(W_enc[k * HID + n]);
    }
    __syncthreads();
    int wave = tid >> 6, lane = tid & 63;
    long m0 = (long)blockIdx.x * 64 + wave * 16;
    int arow = lane & 15, kq = lane >> 4;
    f32x4 acc[16];
    f32x4 z4 = {0.f, 0.f, 0.f, 0.f};
#pragma unroll
    for (int i = 0; i < 16; i++) acc[i] = z4;
#pragma unroll
    for (int kk = 0; kk < OBS; kk += 32) {
        const float* ap = x + (m0 + arow) * OBS + kk + kq * 8;
        float4 a0 = *(const float4*)ap;
        float4 a1 = *(const float4*)(ap + 4);
        short8 af;
        af[0] = (short)f2bf(a0.x); af[1] = (short)f2bf(a0.y);
        af[2] = (short)f2bf(a0.z); af[3] = (short)f2bf(a0.w);
        af[4] = (short)f2bf(a1.x); af[5] = (short)f2bf(a1.y);
        af[6] = (short)f2bf(a1.z); af[7] = (short)f2bf(a1.w);
#pragma unroll
        for (int nt = 0; nt < 16; nt++) {
            int n = nt * 16 + arow;
            int byte = ((n * OBS + kk + kq * 8) * 2) ^ ((n & 7) << 4);
            short8 bf = *(const short8*)((char*)wlds + byte);
            acc[nt] = __builtin_amdgcn_mfma_f32_16x16x32_bf16(af, bf, acc[nt], 0, 0, 0);
        }
    }
#pragma unroll
    for (int nt = 0; nt < 16; nt++) {
        int col = nt * 16 + (lane & 15);
        float bias = b_enc[col];
#pragma unroll
        for (int j = 0; j < 4; j++) {
            long row = m0 + kq * 4 + j;
            float z = acc[nt][j] + bias;
            float zc = 0.79788456f * (z + 0.044715f * z * z * z);
            float g = 0.5f * z * (1.f + tanhf_(zc));
            feats[row * HID + col] = f2bf(g);
        }
    }
}

// Parallel poll: lane i (<32) waits for flag[i] != 0 (call with tid < 64 only).
__device__ __forceinline__ void spin_flags(const uint32_t* fl, int lane) {
    const uint32_t* p = fl + (lane & 31);
    while (true) {
        uint32_t got = (lane < 32)
            ? __hip_atomic_load(p, __ATOMIC_RELAXED, __HIP_MEMORY_SCOPE_AGENT) : 1u;
        if (__all(got != 0)) break;
    }
}

// ---------------- Persistent LSTM scan (flag barrier, L3-coherent bf16 ring) ----------------
// 256 WGs = 8 batch-groups x 32 slices; LDS 104.5KB -> exactly 1 WG/CU, all resident.
__global__ __launch_bounds__(256) void scan_kernel(
    const float* __restrict__ Wi, const float* __restrict__ Wh,
    const float* __restrict__ b_lstm, const unsigned short* __restrict__ feats,
    uint32_t* __restrict__ ring, uint32_t* __restrict__ flags,
    uint32_t* __restrict__ hs32) {
    __shared__ unsigned short whs[GCOLS * HSZ];   // [n=64][k=512] bf16 swizzled, 64KB
    __shared__ unsigned short wis[GCOLS * HID];   // [n=64][k=256] bf16 swizzled, 32KB
    __shared__ float zt[RPG][68];                 // 32x64 z-tile, +4 pad, 8.5KB
    const int tid = threadIdx.x;
    const int g = blockIdx.x & 7;
    const int slice = blockIdx.x >> 3;
    const int rowg = g * RPG;

    // Stage Wh/Wi slices: LDS col n -> global gate col (n&3)*512 + slice*16 + (n>>2)
    for (int idx = tid; idx < GCOLS * HSZ; idx += 256) {
        int n = idx & 63, k = idx >> 6;
        int colg = (n & 3) * HSZ + slice * HCS + (n >> 2);
        int byte = ((n * HSZ + k) * 2) ^ ((n & 7) << 4);
        *(unsigned short*)((char*)whs + byte) = f2bf(Wh[k * 2048 + colg]);
    }
    for (int idx = tid; idx < GCOLS * HID; idx += 256) {
        int n = idx & 63, k = idx >> 6;
        int colg = (n & 3) * HSZ + slice * HCS + (n >> 2);
        int byte = ((n * HID + k) * 2) ^ ((n & 7) << 4);
        *(unsigned short*)((char*)wis + byte) = f2bf(Wi[k * 2048 + colg]);
    }
    // gate-phase ownership: thread -> (row grow, h-col pair {2hp, 2hp+1})
    const int grow = tid >> 3, hp = tid & 7;
    float bl0[4], bl1[4];
#pragma unroll
    for (int q = 0; q < 4; q++) {
        bl0[q] = b_lstm[q * HSZ + slice * HCS + 2 * hp];
        bl1[q] = b_lstm[q * HSZ + slice * HCS + 2 * hp + 1];
    }
    float c0 = 0.f, c1 = 0.f;
    const int wave = tid >> 6, lane = tid & 63;
    const int wr = (wave >> 1) * 16, wc = (wave & 1) * 32;
    const int arow = lane & 15, kq = lane >> 4;
    __syncthreads();

    for (int t = 0; t < T_STEPS; ++t) {
        f32x4 acc0 = {0.f, 0.f, 0.f, 0.f};
        f32x4 acc1 = {0.f, 0.f, 0.f, 0.f};
        // x-gate contribution (independent of h): issue before waiting on peers
        const unsigned short* fr = feats + ((long)t * BATCH + rowg + wr + arow) * HID + kq * 8;
#pragma unroll
        for (int kk = 0; kk < HID; kk += 32) {
            short8 af = *(const short8*)(fr + kk);
            int n0 = wc + arow, n1 = wc + 16 + arow;
            short8 b0 = *(const short8*)((char*)wis + (((n0 * HID + kk + kq * 8) * 2) ^ ((n0 & 7) << 4)));
            short8 b1 = *(const short8*)((char*)wis + (((n1 * HID + kk + kq * 8) * 2) ^ ((n1 & 7) << 4)));
            acc0 = __builtin_amdgcn_mfma_f32_16x16x32_bf16(af, b0, acc0, 0, 0, 0);
            acc1 = __builtin_amdgcn_mfma_f32_16x16x32_bf16(af, b1, acc1, 0, 0, 0);
        }
        __builtin_amdgcn_sched_barrier(0);   // keep x-gate work above the spin
        if (t > 0) {
            if (tid < 64) spin_flags(flags + ((long)g * T_STEPS + t - 1) * 32, lane);
            __syncthreads();
            // coherent loads of h (bf16, hi only): 16 x 16B per lane, one L3 round trip
            const char* hb = (const char*)ring + ((t - 1) & 3) * (RING_SLOT_W * 4)
                           + (rowg + wr + arow) * (HSZ * 2) + kq * 16;
            i32x4 H[16];
            GLD4(H[0],  H[1],  H[2],  H[3],  hb, 0,   64,  128, 192);
            GLD4(H[4],  H[5],  H[6],  H[7],  hb, 256, 320, 384, 448);
            GLD4(H[8],  H[9],  H[10], H[11], hb, 512, 576, 640, 704);
            GLD4(H[12], H[13], H[14], H[15], hb, 768, 832, 896, 960);
            asm volatile("s_waitcnt vmcnt(0)" ::: "memory");
            __builtin_amdgcn_sched_barrier(0);
#pragma unroll
            for (int i = 0; i < 16; i++) {
                int n0 = wc + arow, n1 = wc + 16 + arow;
                int kk = i * 32 + kq * 8;
                short8 b0 = *(const short8*)((char*)whs + (((n0 * HSZ + kk) * 2) ^ ((n0 & 7) << 4)));
                short8 b1 = *(const short8*)((char*)whs + (((n1 * HSZ + kk) * 2) ^ ((n1 & 7) << 4)));
                short8 ah = __builtin_bit_cast(short8, H[i]);
                acc0 = __builtin_amdgcn_mfma_f32_16x16x32_bf16(ah, b0, acc0, 0, 0, 0);
                acc1 = __builtin_amdgcn_mfma_f32_16x16x32_bf16(ah, b1, acc1, 0, 0, 0);
            }
        }
        // z tile -> LDS (C/D layout: col=lane&15, row=(lane>>4)*4+j)
#pragma unroll
        for (int j = 0; j < 4; j++) {
            zt[wr + kq * 4 + j][wc + arow]      = acc0[j];
            zt[wr + kq * 4 + j][wc + 16 + arow] = acc1[j];
        }
        __syncthreads();
        // gate math: thread owns (row grow, hcols 2hp, 2hp+1); c stays in registers
        float4 r0 = *(const float4*)&zt[grow][8 * hp];      // i,f,g,o of hcol 2hp
        float4 r1 = *(const float4*)&zt[grow][8 * hp + 4];  // i,f,g,o of hcol 2hp+1
        c0 = sigmoidf_(r0.y + bl0[1]) * c0 + sigmoidf_(r0.x + bl0[0]) * tanhf_(r0.z + bl0[2]);
        c1 = sigmoidf_(r1.y + bl1[1]) * c1 + sigmoidf_(r1.x + bl1[0]) * tanhf_(r1.z + bl1[2]);
        float h0 = sigmoidf_(r0.w + bl0[3]) * tanhf_(c0);
        float h1 = sigmoidf_(r1.w + bl1[3]) * tanhf_(c1);
        uint32_t wv = (uint32_t)f2bf(h0) | ((uint32_t)f2bf(h1) << 16);
        uint32_t* wp = ring + (t & 3) * RING_SLOT_W + (rowg + grow) * 256 + slice * 8 + hp;
        __hip_atomic_store(wp, wv, __ATOMIC_RELAXED, __HIP_MEMORY_SCOPE_AGENT);
        hs32[((long)t * BATCH + rowg + grow) * 256 + slice * 8 + hp] = wv;  // for heads
        __syncthreads();            // drains vmcnt before s_barrier -> stores visible
        if (tid == 0)
            __hip_atomic_store(flags + ((long)g * T_STEPS + t) * 32 + slice, 1u,
                               __ATOMIC_RELAXED, __HIP_MEMORY_SCOPE_AGENT);
    }
}

// ---------------- Heads: mu/sigma/value from hs (separate dispatch) ----------------
__global__ __launch_bounds__(256) void heads_kernel(
    const unsigned short* __restrict__ hs, const float* __restrict__ W_mu,
    const float* __restrict__ b_mu, const float* __restrict__ log_std,
    const float* __restrict__ W_v, const float* __restrict__ b_v,
    float* __restrict__ mu_out, float* __restrict__ sig_out,
    float* __restrict__ val_out) {
    __shared__ unsigned short wlds[32 * HSZ];     // [n=32][k=512]: 0-15 mu, 16 v, rest 0
    int tid = threadIdx.x;
    for (int idx = tid; idx < 32 * HSZ; idx += 256) {
        int n = idx & 31, k = idx >> 5;
        float w = 0.f;
        if (n < 16) w = W_mu[k * 16 + n];
        else if (n == 16) w = W_v[k];
        int byte = ((n * HSZ + k) * 2) ^ ((n & 7) << 4);
        *(unsigned short*)((char*)wlds + byte) = f2bf(w);
    }
    __syncthreads();
    int wave = tid >> 6, lane = tid & 63;
    long m0 = (long)blockIdx.x * 64 + wave * 16;
    int arow = lane & 15, kq = lane >> 4;
    f32x4 acc0 = {0.f, 0.f, 0.f, 0.f}, acc1 = {0.f, 0.f, 0.f, 0.f};
    const unsigned short* hr = hs + (m0 + arow) * HSZ + kq * 8;
#pragma unroll
    for (int kk = 0; kk < HSZ; kk += 32) {
        short8 af = *(const short8*)(hr + kk);
        int n0 = arow;
        int b0 = ((n0 * HSZ + kk + kq * 8) * 2) ^ ((n0 & 7) << 4);
        short8 bf0 = *(const short8*)((char*)wlds + b0);
        acc0 = __builtin_amdgcn_mfma_f32_16x16x32_bf16(af, bf0, acc0, 0, 0, 0);
        int n1 = 16 + arow;
        int b1 = ((n1 * HSZ + kk + kq * 8) * 2) ^ ((n1 & 7) << 4);
        short8 bf1 = *(const short8*)((char*)wlds + b1);
        acc1 = __builtin_amdgcn_mfma_f32_16x16x32_bf16(af, bf1, acc1, 0, 0, 0);
    }
    int col = lane & 15;
    float bm = b_mu[col];
    float sg = __expf(log_std[col]);
#pragma unroll
    for (int j = 0; j < 4; j++) {
        long row = m0 + kq * 4 + j;
        mu_out[row * 16 + col]  = acc0[j] + bm;
        sig_out[row * 16 + col] = sg;
    }
    if (col == 0) {
        float bv = b_v[0];
#pragma unroll
        for (int j = 0; j < 4; j++) {
            long row = m0 + kq * 4 + j;
            val_out[row] = acc1[j] + bv;
        }
    }
}

extern "C" void kernel_launch(void* const* d_in, const int* in_sizes, int n_in,
                              void* d_out, int out_size, void* d_ws, size_t ws_size,
                              hipStream_t stream) {
    const float* x      = (const float*)d_in[0];
    const float* W_enc  = (const float*)d_in[1];
    const float* b_enc  = (const float*)d_in[2];
    const float* Wi     = (const float*)d_in[3];
    const float* Wh     = (const float*)d_in[4];
    const float* b_lstm = (const float*)d_in[5];
    const float* W_mu   = (const float*)d_in[6];
    const float* b_mu   = (const float*)d_in[7];
    const float* lstd   = (const float*)d_in[8];
    const float* W_v    = (const float*)d_in[9];
    const float* b_v    = (const float*)d_in[10];

    char* ws = (char*)d_ws;
    uint32_t*       flags = (uint32_t*)ws;                            // 256KB flags
    uint32_t*       ring  = (uint32_t*)(ws + (512 << 10));            // 1MB: 4 slots x 256x512 bf16
    unsigned short* feats = (unsigned short*)(ws + (2048 << 10));     // 33.6MB bf16
    unsigned short* hs    = (unsigned short*)(ws + (2048 << 10) + 33554432); // 67.1MB bf16
    // total ws use: ~102.7MB

    float* mu_out  = (float*)d_out;                 // (T*B,16) f32
    float* sig_out = mu_out + 1048576;              // (T*B,16) f32
    float* val_out = mu_out + 2097152;              // (T*B,)   f32

    hipMemsetAsync(flags, 0, 8 * T_STEPS * 32 * sizeof(uint32_t), stream);
    enc_kernel<<<dim3(1024), dim3(256), 0, stream>>>(x, W_enc, b_enc, feats);
    scan_kernel<<<dim3(256), dim3(256), 0, stream>>>(Wi, Wh, b_lstm, feats,
                                                     ring, flags, (uint32_t*)hs);
    heads_kernel<<<dim3(1024), dim3(256), 0, stream>>>(hs, W_mu, b_mu, lstd, W_v, b_v,
                                                       mu_out, sig_out, val_out);
}

// Round 8
// 1020.361 us; speedup vs baseline: 22.8915x; 1.2861x over previous
//
#include <hip/hip_runtime.h>
#include <stdint.h>

#define T_STEPS 256
#define BATCH   256
#define OBS     128
#define HID     256
#define HSZ     512
#define NG      16          // batch groups
#define RPG     16          // batch rows per group
#define NSLICES 16          // h-col slices per group
#define HCS     32          // h-cols per slice
#define GCOLS   128         // gate cols per slice (HCS*4)
#define RING_SLOT_W 65536   // u32 words per ring slot: 256 rows x 256 col-pairs

typedef __attribute__((ext_vector_type(8))) short short8;
typedef __attribute__((ext_vector_type(4))) float f32x4;
typedef __attribute__((ext_vector_type(4))) int   i32x4;

__device__ __forceinline__ unsigned short f2bf(float x) {
    union { float f; uint32_t u; } v; v.f = x;
    uint32_t r = v.u + 0x7FFF + ((v.u >> 16) & 1);
    return (unsigned short)(r >> 16);
}
__device__ __forceinline__ float sigmoidf_(float x) { return 1.f / (1.f + __expf(-x)); }
__device__ __forceinline__ float tanhf_(float x)    { return 1.f - 2.f / (1.f + __expf(2.f * x)); }

// 4 coherent (L1/L2-bypass -> L3) 16B loads; "=&v" early-clobber mandatory.
#define GLD4(d0, d1, d2, d3, p, O0, O1, O2, O3)                                 \
    asm volatile("global_load_dwordx4 %0, %4, off offset:" #O0 " sc0 sc1\n\t"   \
                 "global_load_dwordx4 %1, %4, off offset:" #O1 " sc0 sc1\n\t"   \
                 "global_load_dwordx4 %2, %4, off offset:" #O2 " sc0 sc1\n\t"   \
                 "global_load_dwordx4 %3, %4, off offset:" #O3 " sc0 sc1"       \
                 : "=&v"(d0), "=&v"(d1), "=&v"(d2), "=&v"(d3) : "v"(p))

// ---------------- Encoder: feats = gelu(x @ W_enc + b_enc), bf16 out ----------------
__global__ __launch_bounds__(256) void enc_kernel(
    const float* __restrict__ x, const float* __restrict__ W_enc,
    const float* __restrict__ b_enc, unsigned short* __restrict__ feats) {
    __shared__ unsigned short wlds[HID * OBS];   // [n=256][k=128] bf16 swizzled, 64KB
    int tid = threadIdx.x;
    for (int idx = tid; idx < OBS * HID; idx += 256) {
        int k = idx >> 8, n = idx & 255;
        int byte = ((n * OBS + k) * 2) ^ ((n & 7) << 4);
        *(unsigned short*)((char*)wlds + byte) = f2bf(W_enc[k * HID + n]);
    }
    __syncthreads();
    int wave = tid >> 6, lane = tid & 63;
    long m0 = (long)blockIdx.x * 64 + wave * 16;
    int arow = lane & 15, kq = lane >> 4;
    f32x4 acc[16];
    f32x4 z4 = {0.f, 0.f, 0.f, 0.f};
#pragma unroll
    for (int i = 0; i < 16; i++) acc[i] = z4;
#pragma unroll
    for (int kk = 0; kk < OBS; kk += 32) {
        const float* ap = x + (m0 + arow) * OBS + kk + kq * 8;
        float4 a0 = *(const float4*)ap;
        float4 a1 = *(const float4*)(ap + 4);
        short8 af;
        af[0] = (short)f2bf(a0.x); af[1] = (short)f2bf(a0.y);
        af[2] = (short)f2bf(a0.z); af[3] = (short)f2bf(a0.w);
        af[4] = (short)f2bf(a1.x); af[5] = (short)f2bf(a1.y);
        af[6] = (short)f2bf(a1.z); af[7] = (short)f2bf(a1.w);
#pragma unroll
        for (int nt = 0; nt < 16; nt++) {
            int n = nt * 16 + arow;
            int byte = ((n * OBS + kk + kq * 8) * 2) ^ ((n & 7) << 4);
            short8 bf = *(const short8*)((char*)wlds + byte);
            acc[nt] = __builtin_amdgcn_mfma_f32_16x16x32_bf16(af, bf, acc[nt], 0, 0, 0);
        }
    }
#pragma unroll
    for (int nt = 0; nt < 16; nt++) {
        int col = nt * 16 + (lane & 15);
        float bias = b_enc[col];
#pragma unroll
        for (int j = 0; j < 4; j++) {
            long row = m0 + kq * 4 + j;
            float z = acc[nt][j] + bias;
            float zc = 0.79788456f * (z + 0.044715f * z * z * z);
            float g = 0.5f * z * (1.f + tanhf_(zc));
            feats[row * HID + col] = f2bf(g);
        }
    }
}

// ---------------- Prep: pack Wi into per-lane MFMA B-fragment order ----------------
// Wipk[((s*4+w)*64+l)*16 + f][8]: f = ct*8+i, col n = w*32+ct*16+(l&15),
// colg = (n&3)*512 + s*32 + (n>>2), k = i*32 + (l>>4)*8 + j.
__global__ __launch_bounds__(256) void prep_wi(
    const float* __restrict__ Wi, unsigned short* __restrict__ Wipk) {
    int t = blockIdx.x * 256 + threadIdx.x;        // 65536 threads
    int f = t & 15, l = (t >> 4) & 63, w = (t >> 10) & 3, s = t >> 12;
    int ct = f >> 3, i = f & 7;
    int n = w * 32 + ct * 16 + (l & 15);
    int colg = (n & 3) * HSZ + s * HCS + (n >> 2);
    int kbase = i * 32 + (l >> 4) * 8;
    short8 v;
#pragma unroll
    for (int j = 0; j < 8; j++) v[j] = (short)f2bf(Wi[(kbase + j) * 2048 + colg]);
    *(short8*)(Wipk + (long)t * 8) = v;
}

// Parallel poll: lane i (<16) waits for flag[i] != 0 (call with tid < 64 only).
__device__ __forceinline__ void spin_flags(const uint32_t* fl, int lane) {
    const uint32_t* p = fl + (lane & 15);
    while (true) {
        uint32_t got = (lane < 16)
            ? __hip_atomic_load(p, __ATOMIC_RELAXED, __HIP_MEMORY_SCOPE_AGENT) : 1u;
        if (__all(got != 0)) break;
    }
}

// ---------------- Persistent LSTM scan ----------------
// 256 WGs = 16 groups x 16 slices; LDS 152.25KB -> 1 WG/CU, all resident.
__global__ __launch_bounds__(256) void scan_kernel(
    const float* __restrict__ Wh, const float* __restrict__ b_lstm,
    const unsigned short* __restrict__ feats, const unsigned short* __restrict__ Wipk,
    uint32_t* __restrict__ ring, uint32_t* __restrict__ flags,
    uint32_t* __restrict__ hs32) {
    __shared__ unsigned short whs[GCOLS * HSZ];   // [n=128][k=512] swizzled, 128KB
    __shared__ unsigned short hst[RPG * HSZ];     // h stage [16 rows][512] swizzled, 16KB
    __shared__ float zt[RPG][132];                // 16x128 z-tile +4 pad, 8.25KB
    const int tid = threadIdx.x;
    const int g = blockIdx.x & 15;
    const int slice = blockIdx.x >> 4;
    const int rowg = g * RPG;

    // Stage Wh slice: LDS col n -> global gate col (n&3)*512 + slice*32 + (n>>2)
    for (int idx = tid; idx < GCOLS * HSZ; idx += 256) {
        int n = idx & 127, k = idx >> 7;
        int colg = (n & 3) * HSZ + slice * HCS + (n >> 2);
        int byte = ((n * HSZ + k) * 2) ^ ((n & 7) << 4);
        *(unsigned short*)((char*)whs + byte) = f2bf(Wh[k * 2048 + colg]);
    }
    const int wave = tid >> 6, lane = tid & 63;
    const int wc = wave * 32;                     // 32 gate cols per wave
    const int arow = lane & 15, kq = lane >> 4;
    const int n0 = wc + arow, n1 = wc + 16 + arow;
    // Wi fragments in registers (coalesced 256B read from packed layout)
    short8 wif0[8], wif1[8];
    {
        const short8* wp = (const short8*)Wipk + ((slice * 4 + wave) * 64 + lane) * 16;
#pragma unroll
        for (int i = 0; i < 8; i++) { wif0[i] = wp[i]; wif1[i] = wp[8 + i]; }
    }
    // gate-phase ownership: thread -> (row grow, h-col pair {2hp, 2hp+1})
    const int grow = tid >> 4, hp = tid & 15;
    float bl0[4], bl1[4];
#pragma unroll
    for (int q = 0; q < 4; q++) {
        bl0[q] = b_lstm[q * HSZ + slice * HCS + 2 * hp];
        bl1[q] = b_lstm[q * HSZ + slice * HCS + 2 * hp + 1];
    }
    float c0 = 0.f, c1 = 0.f;
    const int srow = tid >> 4, sc64 = tid & 15;   // h-stage ownership: 64B per thread
    const int sw = (srow & 7) << 4;
    f32x4 z4 = {0.f, 0.f, 0.f, 0.f};
    __syncthreads();

    for (int t = 0; t < T_STEPS; ++t) {
        f32x4 acc0 = z4, acc1 = z4;
        // x-gates: feats A-frags (cached loads) x in-register Wi B-frags
        const char* fb = (const char*)feats + ((long)t * BATCH + rowg + arow) * (HID * 2) + kq * 16;
#pragma unroll
        for (int i = 0; i < 8; i++) {
            short8 af = *(const short8*)(fb + i * 64);
            acc0 = __builtin_amdgcn_mfma_f32_16x16x32_bf16(af, wif0[i], acc0, 0, 0, 0);
            acc1 = __builtin_amdgcn_mfma_f32_16x16x32_bf16(af, wif1[i], acc1, 0, 0, 0);
        }
        __builtin_amdgcn_sched_barrier(0);   // keep x-gate work above the spin
        if (t > 0) {
            if (tid < 64) spin_flags(flags + ((long)g * T_STEPS + t - 1) * 16, lane);
            __syncthreads();
            // stage group's h block (16 rows x 512 bf16) into LDS, one read per byte
            const char* hb = (const char*)ring + ((t - 1) & 3) * (RING_SLOT_W * 4)
                           + (rowg + srow) * 1024 + sc64 * 64;
            i32x4 S0, S1, S2, S3;
            GLD4(S0, S1, S2, S3, hb, 0, 16, 32, 48);
            asm volatile("s_waitcnt vmcnt(0)" ::: "memory");
            __builtin_amdgcn_sched_barrier(0);
            int sb = srow * 1024 + sc64 * 64;
            *(i32x4*)((char*)hst + ((sb +  0) ^ sw)) = S0;
            *(i32x4*)((char*)hst + ((sb + 16) ^ sw)) = S1;
            *(i32x4*)((char*)hst + ((sb + 32) ^ sw)) = S2;
            *(i32x4*)((char*)hst + ((sb + 48) ^ sw)) = S3;
            __syncthreads();
            // h MFMAs: A from swizzled LDS stage, B from swizzled Wh slice
#pragma unroll
            for (int i = 0; i < 16; i++) {
                short8 ah = *(const short8*)((char*)hst
                              + ((arow * 1024 + i * 64 + kq * 16) ^ ((arow & 7) << 4)));
                int kk = i * 32 + kq * 8;
                short8 b0 = *(const short8*)((char*)whs + (((n0 * HSZ + kk) * 2) ^ ((n0 & 7) << 4)));
                short8 b1 = *(const short8*)((char*)whs + (((n1 * HSZ + kk) * 2) ^ ((n1 & 7) << 4)));
                acc0 = __builtin_amdgcn_mfma_f32_16x16x32_bf16(ah, b0, acc0, 0, 0, 0);
                acc1 = __builtin_amdgcn_mfma_f32_16x16x32_bf16(ah, b1, acc1, 0, 0, 0);
            }
        }
        // z tile -> LDS (C/D layout: col=lane&15, row=(lane>>4)*4+j)
#pragma unroll
        for (int j = 0; j < 4; j++) {
            zt[kq * 4 + j][wc + arow]      = acc0[j];
            zt[kq * 4 + j][wc + 16 + arow] = acc1[j];
        }
        __syncthreads();
        // gate math: thread owns (row grow, hcols 2hp, 2hp+1)
        float4 r0 = *(const float4*)&zt[grow][8 * hp];      // i,f,g,o of hcol 2hp
        float4 r1 = *(const float4*)&zt[grow][8 * hp + 4];  // i,f,g,o of hcol 2hp+1
        c0 = sigmoidf_(r0.y + bl0[1]) * c0 + sigmoidf_(r0.x + bl0[0]) * tanhf_(r0.z + bl0[2]);
        c1 = sigmoidf_(r1.y + bl1[1]) * c1 + sigmoidf_(r1.x + bl1[0]) * tanhf_(r1.z + bl1[2]);
        float h0 = sigmoidf_(r0.w + bl0[3]) * tanhf_(c0);
        float h1 = sigmoidf_(r1.w + bl1[3]) * tanhf_(c1);
        uint32_t wv = (uint32_t)f2bf(h0) | ((uint32_t)f2bf(h1) << 16);
        uint32_t* wp = ring + (t & 3) * RING_SLOT_W + (rowg + grow) * 256 + slice * 16 + hp;
        __hip_atomic_store(wp, wv, __ATOMIC_RELAXED, __HIP_MEMORY_SCOPE_AGENT);
        hs32[((long)t * BATCH + rowg + grow) * 256 + slice * 16 + hp] = wv;  // for heads
        __syncthreads();            // drains vmcnt before s_barrier -> stores visible
        if (tid == 0)
            __hip_atomic_store(flags + ((long)g * T_STEPS + t) * 16 + slice, 1u,
                               __ATOMIC_RELAXED, __HIP_MEMORY_SCOPE_AGENT);
    }
}

// ---------------- Heads: mu/sigma/value from hs (separate dispatch) ----------------
__global__ __launch_bounds__(256) void heads_kernel(
    const unsigned short* __restrict__ hs, const float* __restrict__ W_mu,
    const float* __restrict__ b_mu, const float* __restrict__ log_std,
    const float* __restrict__ W_v, const float* __restrict__ b_v,
    float* __restrict__ mu_out, float* __restrict__ sig_out,
    float* __restrict__ val_out) {
    __shared__ unsigned short wlds[32 * HSZ];     // [n=32][k=512]: 0-15 mu, 16 v, rest 0
    int tid = threadIdx.x;
    for (int idx = tid; idx < 32 * HSZ; idx += 256) {
        int n = idx & 31, k = idx >> 5;
        float w = 0.f;
        if (n < 16) w = W_mu[k * 16 + n];
        else if (n == 16) w = W_v[k];
        int byte = ((n * HSZ + k) * 2) ^ ((n & 7) << 4);
        *(unsigned short*)((char*)wlds + byte) = f2bf(w);
    }
    __syncthreads();
    int wave = tid >> 6, lane = tid & 63;
    long m0 = (long)blockIdx.x * 64 + wave * 16;
    int arow = lane & 15, kq = lane >> 4;
    f32x4 acc0 = {0.f, 0.f, 0.f, 0.f}, acc1 = {0.f, 0.f, 0.f, 0.f};
    const unsigned short* hr = hs + (m0 + arow) * HSZ + kq * 8;
#pragma unroll
    for (int kk = 0; kk < HSZ; kk += 32) {
        short8 af = *(const short8*)(hr + kk);
        int n0 = arow;
        int b0 = ((n0 * HSZ + kk + kq * 8) * 2) ^ ((n0 & 7) << 4);
        short8 bf0 = *(const short8*)((char*)wlds + b0);
        acc0 = __builtin_amdgcn_mfma_f32_16x16x32_bf16(af, bf0, acc0, 0, 0, 0);
        int n1 = 16 + arow;
        int b1 = ((n1 * HSZ + kk + kq * 8) * 2) ^ ((n1 & 7) << 4);
        short8 bf1 = *(const short8*)((char*)wlds + b1);
        acc1 = __builtin_amdgcn_mfma_f32_16x16x32_bf16(af, bf1, acc1, 0, 0, 0);
    }
    int col = lane & 15;
    float bm = b_mu[col];
    float sg = __expf(log_std[col]);
#pragma unroll
    for (int j = 0; j < 4; j++) {
        long row = m0 + kq * 4 + j;
        mu_out[row * 16 + col]  = acc0[j] + bm;
        sig_out[row * 16 + col] = sg;
    }
    if (col == 0) {
        float bv = b_v[0];
#pragma unroll
        for (int j = 0; j < 4; j++) {
            long row = m0 + kq * 4 + j;
            val_out[row] = acc1[j] + bv;
        }
    }
}

extern "C" void kernel_launch(void* const* d_in, const int* in_sizes, int n_in,
                              void* d_out, int out_size, void* d_ws, size_t ws_size,
                              hipStream_t stream) {
    const float* x      = (const float*)d_in[0];
    const float* W_enc  = (const float*)d_in[1];
    const float* b_enc  = (const float*)d_in[2];
    const float* Wi     = (const float*)d_in[3];
    const float* Wh     = (const float*)d_in[4];
    const float* b_lstm = (const float*)d_in[5];
    const float* W_mu   = (const float*)d_in[6];
    const float* b_mu   = (const float*)d_in[7];
    const float* lstd   = (const float*)d_in[8];
    const float* W_v    = (const float*)d_in[9];
    const float* b_v    = (const float*)d_in[10];

    char* ws = (char*)d_ws;
    uint32_t*       flags = (uint32_t*)ws;                            // 256KB flags
    uint32_t*       ring  = (uint32_t*)(ws + (512 << 10));            // 1MB ring
    unsigned short* Wipk  = (unsigned short*)(ws + (1536 << 10));     // 1MB packed Wi
    unsigned short* feats = (unsigned short*)(ws + (3584 << 10));     // 33.6MB bf16
    unsigned short* hs    = (unsigned short*)(ws + (3584 << 10) + 33554432); // 67.1MB
    // total ws use: ~104MB

    float* mu_out  = (float*)d_out;                 // (T*B,16) f32
    float* sig_out = mu_out + 1048576;              // (T*B,16) f32
    float* val_out = mu_out + 2097152;              // (T*B,)   f32

    hipMemsetAsync(flags, 0, NG * T_STEPS * NSLICES * sizeof(uint32_t), stream);
    prep_wi<<<dim3(256), dim3(256), 0, stream>>>(Wi, Wipk);
    enc_kernel<<<dim3(1024), dim3(256), 0, stream>>>(x, W_enc, b_enc, feats);
    scan_kernel<<<dim3(256), dim3(256), 0, stream>>>(Wh, b_lstm, feats, Wipk,
                                                     ring, flags, (uint32_t*)hs);
    heads_kernel<<<dim3(1024), dim3(256), 0, stream>>>(hs, W_mu, b_mu, lstd, W_v, b_v,
                                                       mu_out, sig_out, val_out);
}